// Round 7
// baseline (183.403 us; speedup 1.0000x reference)
//
#include <hip/hip_runtime.h>
#include <hip/hip_bf16.h>

// LoRALinear: y = x @ W^T + b + 1.0 * ((x @ A^T) @ B^T)
// W_eff = W + B@A (bf16, ws[0..2MB)).
// Fused GEMM 128x128x64, 4 waves, 64 KB LDS -> 2 blocks/CU so prologue/
// epilogue/waits of one block overlap compute of the other.
// A (x fp32) reg-staged with fused fp32->bf16 cvt (1-tile gap, R5-proven);
// B via global_load_lds staged 2 tiles ahead (B region dead after p1).

typedef __bf16 bf16;
typedef bf16 bf16x8 __attribute__((ext_vector_type(8)));
typedef float f32x4 __attribute__((ext_vector_type(4)));

constexpr int K_DIM = 1024;
constexpr int N_DIM = 1024;
constexpr int M_DIM = 8 * 4096;
constexpr int NT = K_DIM / 64;  // 16 K-tiles
constexpr float SCALING = 16.0f / 16.0f;

// ---------------- W_eff = W + B@A, cast to bf16 ----------------
__global__ __launch_bounds__(256) void weff_kernel(
    const float* __restrict__ W, const float* __restrict__ A,
    const float* __restrict__ B, bf16* __restrict__ weff) {
  const int o = blockIdx.x;
  const int tid = threadIdx.x;
  float br[16];
#pragma unroll
  for (int r = 0; r < 16; ++r) br[r] = B[o * 16 + r];
#pragma unroll
  for (int j = 0; j < 4; ++j) {
    const int k = tid + j * 256;
    float s = W[o * K_DIM + k];
#pragma unroll
    for (int r = 0; r < 16; ++r) s += SCALING * br[r] * A[r * K_DIM + k];
    weff[o * K_DIM + k] = (bf16)s;
  }
}

// ---------------- fused 128x128 GEMM, 2 blocks/CU ----------------
__device__ __forceinline__ void async16(const void* g, void* l) {
  __builtin_amdgcn_global_load_lds(
      (const __attribute__((address_space(1))) void*)g,
      (__attribute__((address_space(3))) void*)l, 16, 0, 0);
}
#define BAR() __builtin_amdgcn_s_barrier()
#define LGKM0()                                        \
  do {                                                 \
    asm volatile("s_waitcnt lgkmcnt(0)" ::: "memory"); \
    __builtin_amdgcn_sched_barrier(0);                 \
  } while (0)
#define VMW(n) asm volatile("s_waitcnt vmcnt(" #n ")" ::: "memory")
#define MFMA(d, a, b) d = __builtin_amdgcn_mfma_f32_16x16x32_bf16(a, b, d, 0, 0, 0)

// LDS (bf16 elems): A buf p at [p*8192], B buf p at [16384 + p*8192].
// Row = 64 bf16 = 8 chunks of 16 B; stored slot s holds global chunk s^(row&7).

__global__ __launch_bounds__(256, 2) void gemm128(
    const float* __restrict__ Xf, const bf16* __restrict__ Wf,
    const float* __restrict__ bias, float* __restrict__ Y) {
  __shared__ __align__(16) bf16 smem[32768];  // 64 KiB

  const int tid = threadIdx.x;
  const int lane = tid & 63;
  const int wid = tid >> 6;
  const int wm = wid >> 1;  // 0..1
  const int wn = wid & 1;   // 0..1
  const int l15 = lane & 15;
  const int lq = lane >> 4;

  // XCD-aware bijective swizzle (2048 % 8 == 0); bn fastest within an XCD
  // chunk -> x-slab L2 reuse.
  const int bid = blockIdx.x;
  const int wgid = (bid & 7) * 256 + (bid >> 3);
  const int bm = wgid >> 3;  // 0..255
  const int bn = wgid & 7;   // 0..7
  const long m0 = (long)bm * 128;
  const int n0 = bn * 128;

  // ---- B staging (global_load_lds, pre-swizzled source) ----
  const int brow = tid >> 3;               // 0..31
  const int bch = (tid & 7) ^ (brow & 7);  // inverse of read swizzle
  const bf16* wsrc = Wf + (long)(n0 + brow) * K_DIM + bch * 8;
  auto stageB = [&](int tt) {
    bf16* dst = smem + 16384 + (tt & 1) * 8192 + tid * 8;
    const bf16* s = wsrc + tt * 64;
#pragma unroll
    for (int j = 0; j < 4; ++j)
      async16(s + (long)32 * j * K_DIM, dst + 2048 * j);
  };

  // ---- A staging (reg fp32 -> cvt -> swizzled ds_write) ----
  const int arow = tid >> 1;  // 0..127
  const int ahalf = tid & 1;  // which 32-f32 half of the row
  const int ar7 = arow & 7;
  const float* asrc = Xf + (m0 + arow) * K_DIM + ahalf * 32;

  f32x4 rA[8];  // one in-flight A set (128 B/thread)
  auto loadA = [&](int tt) {
    const float* s = asrc + tt * 64;
#pragma unroll
    for (int i = 0; i < 8; ++i) rA[i] = *(const f32x4*)(s + i * 4);
  };
  auto writeA = [&](int tt) {
    bf16* dst = smem + (tt & 1) * 8192 + arow * 64;
#pragma unroll
    for (int j = 0; j < 4; ++j) {
      bf16x8 c;
#pragma unroll
      for (int q = 0; q < 4; ++q) {
        c[q] = (bf16)rA[2 * j][q];
        c[4 + q] = (bf16)rA[2 * j + 1][q];
      }
      *(bf16x8*)(dst + ((ahalf * 4 + j) ^ ar7) * 8) = c;
    }
  };

  // fragment read offsets; kk=1 -> elem offset ^ 32
  const int key = l15 & 7;
  const int eA = (wm * 64 + l15) * 64 + (lq ^ key) * 8;
  const int eB = (wn * 64 + l15) * 64 + (lq ^ key) * 8;

  f32x4 acc[4][4] = {};

  // ---- prologue ----
  loadA(0);
  stageB(0);
  stageB(1);
  writeA(0);  // cvt waits loadA(0) only (oldest); B(0),B(1) stay in flight
  loadA(1);
  VMW(12);  // retire B(0); keep B(1)+loadA(1) (12) in flight
  asm volatile("s_waitcnt lgkmcnt(0)" ::: "memory");
  BAR();

  for (int t = 0; t < NT; ++t) {
    const bf16* Ab = smem + (t & 1) * 8192;
    const bf16* Bb = smem + 16384 + (t & 1) * 8192;
    bf16x8 Bf0[4], Bf1[4];
    {  // p1: A kk0 frags + ALL B frags; MFMA kk0
      bf16x8 Af[4];
#pragma unroll
      for (int mi = 0; mi < 4; ++mi)
        Af[mi] = *(const bf16x8*)(Ab + eA + mi * 1024);
#pragma unroll
      for (int ni = 0; ni < 4; ++ni)
        Bf0[ni] = *(const bf16x8*)(Bb + eB + ni * 1024);
#pragma unroll
      for (int ni = 0; ni < 4; ++ni)
        Bf1[ni] = *(const bf16x8*)(Bb + (eB ^ 32) + ni * 1024);
      BAR();
      LGKM0();
      __builtin_amdgcn_s_setprio(1);
#pragma unroll
      for (int m = 0; m < 4; ++m)
#pragma unroll
        for (int n = 0; n < 4; ++n) MFMA(acc[m][n], Af[m], Bf0[n]);
      __builtin_amdgcn_s_setprio(0);
      BAR();
    }
    {  // p2: A kk1 frags; cvt+write A(t+1); reload A(t+2); stage B(t+2)
      bf16x8 Af[4];
#pragma unroll
      for (int mi = 0; mi < 4; ++mi)
        Af[mi] = *(const bf16x8*)(Ab + (eA ^ 32) + mi * 1024);
      if (t < NT - 1) writeA(t + 1);  // waits loadA(t+1); keeps B(t+1)
      if (t < NT - 2) loadA(t + 2);   // WAR-safe: issued after cvt reads
      if (t < NT - 2) stageB(t + 2);  // B region of buf(t&1) dead after p1
      BAR();
      LGKM0();
      __builtin_amdgcn_s_setprio(1);
#pragma unroll
      for (int m = 0; m < 4; ++m)
#pragma unroll
        for (int n = 0; n < 4; ++n) MFMA(acc[m][n], Af[m], Bf1[n]);
      __builtin_amdgcn_s_setprio(0);
      // boundary: B(t+1) (older than this tile's 12 issues) must retire.
      if (t < NT - 2) {
        VMW(12);
      } else if (t == NT - 2) {
        VMW(0);  // B(NT-1) was issued AFTER loadA(NT-1): must drain here
      }
      BAR();
    }
  }

  // epilogue: C/D layout col = lane&15, row = lq*4 + reg
  const long crow0 = m0 + wm * 64 + lq * 4;
  const int ccol0 = n0 + wn * 64 + l15;
  float bn4[4];
#pragma unroll
  for (int n = 0; n < 4; ++n) bn4[n] = bias[ccol0 + n * 16];
#pragma unroll
  for (int m = 0; m < 4; ++m)
#pragma unroll
    for (int n = 0; n < 4; ++n) {
      const int col = ccol0 + n * 16;
#pragma unroll
      for (int i = 0; i < 4; ++i)
        Y[(crow0 + m * 16 + i) * N_DIM + col] = acc[m][n][i] + bn4[n];
    }
}

extern "C" void kernel_launch(void* const* d_in, const int* in_sizes, int n_in,
                              void* d_out, int out_size, void* d_ws, size_t ws_size,
                              hipStream_t stream) {
  const float* x = (const float*)d_in[0];
  const float* W = (const float*)d_in[1];
  const float* b = (const float*)d_in[2];
  const float* lA = (const float*)d_in[3];
  const float* lB = (const float*)d_in[4];
  float* y = (float*)d_out;

  bf16* weff = (bf16*)d_ws;  // 2 MB

  weff_kernel<<<dim3(1024), dim3(256), 0, stream>>>(W, lA, lB, weff);

  const int grid = (M_DIM / 128) * (N_DIM / 128);  // 2048
  gemm128<<<dim3(grid), dim3(256), 0, stream>>>(x, weff, b, y);
}

// Round 8
// 152.602 us; speedup vs baseline: 1.2018x; 1.2018x over previous
//
#include <hip/hip_runtime.h>
#include <hip/hip_bf16.h>

// LoRALinear: y = x @ W^T + b + 1.0 * ((x @ A^T) @ B^T)
// W_eff = W + B@A (bf16, ws[0..2MB)).
// Fused GEMM 256x256, BK=32, 8 waves, TRIPLE-buffered LDS (144 KB):
//   A staged as RAW FP32 via global_load_lds (no reg round-trip),
//   converted fp32->bf16 in-register at fragment-load time.
//   B staged bf16 via global_load_lds, rows pair-packed into 128-B lines.
// Stage tile t+2 during tile t; boundary s_waitcnt vmcnt(6) (counted, never
// 0 until tail). Phases contain only {ds_read, lgkm, cvt, MFMA} + barriers.

typedef __bf16 bf16;
typedef bf16 bf16x8 __attribute__((ext_vector_type(8)));
typedef float f32x4 __attribute__((ext_vector_type(4)));

constexpr int K_DIM = 1024;
constexpr int N_DIM = 1024;
constexpr int M_DIM = 8 * 4096;
constexpr int NT = K_DIM / 32;  // 32 K-tiles of BK=32
constexpr float SCALING = 16.0f / 16.0f;

// ---------------- W_eff = W + B@A, cast to bf16 ----------------
__global__ __launch_bounds__(256) void weff_kernel(
    const float* __restrict__ W, const float* __restrict__ A,
    const float* __restrict__ B, bf16* __restrict__ weff) {
  const int o = blockIdx.x;
  const int tid = threadIdx.x;
  float br[16];
#pragma unroll
  for (int r = 0; r < 16; ++r) br[r] = B[o * 16 + r];
#pragma unroll
  for (int j = 0; j < 4; ++j) {
    const int k = tid + j * 256;
    float s = W[o * K_DIM + k];
#pragma unroll
    for (int r = 0; r < 16; ++r) s += SCALING * br[r] * A[r * K_DIM + k];
    weff[o * K_DIM + k] = (bf16)s;
  }
}

// ---------------- fused GEMM ----------------
__device__ __forceinline__ void async16(const void* g, void* l) {
  __builtin_amdgcn_global_load_lds(
      (const __attribute__((address_space(1))) void*)g,
      (__attribute__((address_space(3))) void*)l, 16, 0, 0);
}
#define BAR() __builtin_amdgcn_s_barrier()
#define LGKM0()                                        \
  do {                                                 \
    asm volatile("s_waitcnt lgkmcnt(0)" ::: "memory"); \
    __builtin_amdgcn_sched_barrier(0);                 \
  } while (0)
#define VMW(n) asm volatile("s_waitcnt vmcnt(" #n ")" ::: "memory")
#define MFMA(d, a, b) d = __builtin_amdgcn_mfma_f32_16x16x32_bf16(a, b, d, 0, 0, 0)

// LDS: smemA = 3 bufs x 8192 f32 (256 rows x 32 f32, row=128B=8 chunks,
//       stored chunk s holds global chunk s^(row&7)).
//      smemB = 3 bufs x 8192 bf16 (128 lines x 64 bf16; line L packs rows
//       2L,2L+1 (32 bf16 each); stored chunk s holds packed chunk s^(L&7);
//       packed chunk cg: row parity = cg>>2, k-chunk = cg&3).

__global__ __launch_bounds__(512, 2) void gemm32(
    const float* __restrict__ Xf, const bf16* __restrict__ Wf,
    const float* __restrict__ bias, float* __restrict__ Y) {
  __shared__ __align__(16) float smemA[3 * 8192];  // 96 KiB
  __shared__ __align__(16) bf16 smemB[3 * 8192];   // 48 KiB

  const int tid = threadIdx.x;
  const int lane = tid & 63;
  const int wid = tid >> 6;
  const int wm = wid >> 2;  // 0..1
  const int wn = wid & 3;   // 0..3
  const int l15 = lane & 15;
  const int lq = lane >> 4;

  // XCD-aware bijective swizzle (512 % 8 == 0)
  const int bid = blockIdx.x;
  const int wgid = (bid & 7) * 64 + (bid >> 3);
  const int bm = wgid >> 2;  // 0..127
  const int bn = wgid & 3;   // 0..3
  const long m0 = (long)bm * 256;
  const int n0 = bn * 256;

  // ---- staging addresses (pre-permuted global sources) ----
  const int g8 = (tid & 7) ^ ((tid >> 3) & 7);  // swizzled chunk, all j
  // A: stored chunk sa=j*512+tid -> row=(tid>>3)+j*64, src col-chunk g8 (f32 x4)
  const float* xsrcA = Xf + (m0 + (tid >> 3)) * K_DIM + g8 * 4;
  // B: stored chunk sb=j*512+tid -> line=(tid>>3)+j*64, packed chunk g8:
  //    srcRow = 2*line + (g8>>2), k-chunk = g8&3 (bf16 x8)
  const bf16* xsrcB =
      Wf + (long)(n0 + 2 * (tid >> 3) + (g8 >> 2)) * K_DIM + (g8 & 3) * 8;

  auto stageA = [&](int tt, int cur) {
    float* dst = smemA + cur * 8192 + tid * 4;
    const float* s = xsrcA + tt * 32;
#pragma unroll
    for (int j = 0; j < 4; ++j)
      async16(s + (long)j * 64 * K_DIM, dst + j * 2048);
  };
  auto stageB = [&](int tt, int cur) {
    bf16* dst = smemB + cur * 8192 + tid * 8;
    const bf16* s = xsrcB + tt * 32;
#pragma unroll
    for (int j = 0; j < 2; ++j)
      async16(s + (long)j * 128 * K_DIM, dst + j * 4096);
  };

  // ---- fragment read offsets ----
  const int keyA = l15 & 7;
  const int eA0 = (wm * 128 + l15) * 32 + ((2 * lq) ^ keyA) * 4;      // f32 idx
  const int eA1 = (wm * 128 + l15) * 32 + ((2 * lq + 1) ^ keyA) * 4;  // f32 idx
  const int cB = (lq + 4 * (l15 & 1)) ^ ((l15 >> 1) & 7);
  const int eB0 = (wn * 32 + (l15 >> 1)) * 64 + cB * 8;  // bf16 idx, ni=0

  f32x4 acc[8][4] = {};

  // ---- prologue: stage tiles 0 and 1 (6 ops each) ----
  stageA(0, 0);
  stageB(0, 0);
  stageA(1, 1);
  stageB(1, 1);
  VMW(6);  // tile0 retired; tile1's 6 stay in flight
  BAR();

  int cR = 0;  // buffer for tile t
  int cS = 2;  // buffer for tile t+2
  for (int t = 0; t < NT; ++t) {
    const float* Ab = smemA + cR * 8192;
    const bf16* Bb = smemB + cR * 8192;
    bf16x8 Bf[4];
    {  // p1: stage A(t+2); read A mi0-3 (fp32) + all B; cvt; MFMA mi0-3
      if (t + 2 < NT) stageA(t + 2, cS);
      f32x4 alo[4], ahi[4];
#pragma unroll
      for (int mi = 0; mi < 4; ++mi) {
        alo[mi] = *(const f32x4*)(Ab + eA0 + mi * 512);
        ahi[mi] = *(const f32x4*)(Ab + eA1 + mi * 512);
      }
#pragma unroll
      for (int ni = 0; ni < 4; ++ni)
        Bf[ni] = *(const bf16x8*)(Bb + eB0 + ni * 512);
      BAR();
      LGKM0();
      bf16x8 Af[4];
#pragma unroll
      for (int mi = 0; mi < 4; ++mi)
#pragma unroll
        for (int j = 0; j < 4; ++j) {
          Af[mi][j] = (bf16)alo[mi][j];
          Af[mi][4 + j] = (bf16)ahi[mi][j];
        }
      __builtin_amdgcn_s_setprio(1);
#pragma unroll
      for (int m = 0; m < 4; ++m)
#pragma unroll
        for (int n = 0; n < 4; ++n) MFMA(acc[m][n], Af[m], Bf[n]);
      __builtin_amdgcn_s_setprio(0);
      BAR();
    }
    {  // p2: stage B(t+2); read A mi4-7; cvt; MFMA mi4-7; counted boundary
      if (t + 2 < NT) stageB(t + 2, cS);
      f32x4 alo[4], ahi[4];
#pragma unroll
      for (int mi = 0; mi < 4; ++mi) {
        alo[mi] = *(const f32x4*)(Ab + eA0 + 2048 + mi * 512);
        ahi[mi] = *(const f32x4*)(Ab + eA1 + 2048 + mi * 512);
      }
      BAR();
      LGKM0();
      bf16x8 Af[4];
#pragma unroll
      for (int mi = 0; mi < 4; ++mi)
#pragma unroll
        for (int j = 0; j < 4; ++j) {
          Af[mi][j] = (bf16)alo[mi][j];
          Af[mi][4 + j] = (bf16)ahi[mi][j];
        }
      __builtin_amdgcn_s_setprio(1);
#pragma unroll
      for (int m = 0; m < 4; ++m)
#pragma unroll
        for (int n = 0; n < 4; ++n) MFMA(acc[4 + m][n], Af[m], Bf[n]);
      __builtin_amdgcn_s_setprio(0);
      // boundary: tile t+1's 6 loads (older) must retire; tile t+2's 6
      // (issued this tile) stay in flight.
      if (t < NT - 2) {
        VMW(6);
      } else if (t == NT - 2) {
        VMW(0);
      }
      BAR();
    }
    cR = (cR == 2) ? 0 : cR + 1;
    cS = (cS == 2) ? 0 : cS + 1;
  }

  // epilogue: C/D layout col = lane&15, row = lq*4 + reg
  const long crow0 = m0 + wm * 128 + lq * 4;
  const int ccol0 = n0 + wn * 64 + l15;
  float bn4[4];
#pragma unroll
  for (int n = 0; n < 4; ++n) bn4[n] = bias[ccol0 + n * 16];
#pragma unroll
  for (int m = 0; m < 8; ++m)
#pragma unroll
    for (int n = 0; n < 4; ++n) {
      const int col = ccol0 + n * 16;
#pragma unroll
      for (int i = 0; i < 4; ++i)
        Y[(crow0 + m * 16 + i) * N_DIM + col] = acc[m][n][i] + bn4[n];
    }
}

extern "C" void kernel_launch(void* const* d_in, const int* in_sizes, int n_in,
                              void* d_out, int out_size, void* d_ws, size_t ws_size,
                              hipStream_t stream) {
  const float* x = (const float*)d_in[0];
  const float* W = (const float*)d_in[1];
  const float* b = (const float*)d_in[2];
  const float* lA = (const float*)d_in[3];
  const float* lB = (const float*)d_in[4];
  float* y = (float*)d_out;

  bf16* weff = (bf16*)d_ws;  // 2 MB

  weff_kernel<<<dim3(1024), dim3(256), 0, stream>>>(W, lA, lB, weff);

  const int grid = (M_DIM / 256) * (N_DIM / 256);  // 512
  gemm32<<<dim3(grid), dim3(512), 0, stream>>>(x, weff, b, y);
}

// Round 9
// 115.641 us; speedup vs baseline: 1.5860x; 1.3196x over previous
//
#include <hip/hip_runtime.h>
#include <hip/hip_bf16.h>

// LoRALinear: y = x @ W^T + b + 1.0 * ((x @ A^T) @ B^T)
// W_eff = W + B@A (bf16, ws[0..2MB)).
// Fused GEMM 256x256x64, 8-phase counted-vmcnt (T1+T2+T3+T4+T5).
// A (x fp32) reg-staged with fused fp32->bf16 cvt (R5 single-set pipeline):
//   p3/p4 of tile t: cvt+ds_write A(t+1) (regs loaded at p3/p4 of t-1),
//   then re-issue loads for A(t+2) into the same regs (WAR-safe).
// R8 change: COUNTED lgkmcnt(2) at p3/p4 MFMA gates -- the 2 ds_writes of
// A(t+1) retire under the MFMA cluster instead of being drained at the gate;
// lgkmcnt(0) after p4's MFMA restores cross-wave visibility before the
// boundary barrier. (DS ops complete in-order per wave, so lgkmcnt(2) ==
// "4 frag reads done, 2 writes may be outstanding".)

typedef __bf16 bf16;
typedef bf16 bf16x8 __attribute__((ext_vector_type(8)));
typedef float f32x4 __attribute__((ext_vector_type(4)));

constexpr int K_DIM = 1024;
constexpr int N_DIM = 1024;
constexpr int M_DIM = 8 * 4096;
constexpr int NT = K_DIM / 64;  // 16 K-tiles
constexpr float SCALING = 16.0f / 16.0f;

// ---------------- W_eff = W + B@A, cast to bf16 ----------------
__global__ __launch_bounds__(256) void weff_kernel(
    const float* __restrict__ W, const float* __restrict__ A,
    const float* __restrict__ B, bf16* __restrict__ weff) {
  const int o = blockIdx.x;
  const int tid = threadIdx.x;
  float br[16];
#pragma unroll
  for (int r = 0; r < 16; ++r) br[r] = B[o * 16 + r];
#pragma unroll
  for (int j = 0; j < 4; ++j) {
    const int k = tid + j * 256;
    float s = W[o * K_DIM + k];
#pragma unroll
    for (int r = 0; r < 16; ++r) s += SCALING * br[r] * A[r * K_DIM + k];
    weff[o * K_DIM + k] = (bf16)s;
  }
}

// ---------------- fused 8-phase 256x256 GEMM ----------------
__device__ __forceinline__ void async16(const void* g, void* l) {
  __builtin_amdgcn_global_load_lds(
      (const __attribute__((address_space(1))) void*)g,
      (__attribute__((address_space(3))) void*)l, 16, 0, 0);
}
#define BAR() __builtin_amdgcn_s_barrier()
#define LGKM(n)                                              \
  do {                                                       \
    asm volatile("s_waitcnt lgkmcnt(" #n ")" ::: "memory");  \
    __builtin_amdgcn_sched_barrier(0);                       \
  } while (0)
#define VMW(n) asm volatile("s_waitcnt vmcnt(" #n ")" ::: "memory")
#define MFMA(d, a, b) d = __builtin_amdgcn_mfma_f32_16x16x32_bf16(a, b, d, 0, 0, 0)

// LDS (bf16 elems): buf c at c*32768; A [0,16384), B [16384,32768).
// Row = 64 bf16 = 8 chunks of 16 B; stored chunk s holds global chunk s^(row&7).

__global__ __launch_bounds__(512, 2) void gemm8f(
    const float* __restrict__ Xf, const bf16* __restrict__ Wf,
    const float* __restrict__ bias, float* __restrict__ Y) {
  __shared__ __align__(16) bf16 smem[65536];  // 128 KiB

  const int tid = threadIdx.x;
  const int lane = tid & 63;
  const int wid = tid >> 6;
  const int wm = wid >> 2;  // 0..1
  const int wn = wid & 3;   // 0..3
  const int l15 = lane & 15;
  const int lq = lane >> 4;

  // XCD-aware bijective swizzle (512 % 8 == 0)
  const int bid = blockIdx.x;
  const int wgid = (bid & 7) * 64 + (bid >> 3);
  const int bm = wgid >> 2;  // 0..127
  const int bn = wgid & 3;   // 0..3
  const long m0 = (long)bm * 256;
  const int n0 = bn * 256;

  // ---- B staging (global_load_lds, pre-swizzled source) ----
  const int srow = tid >> 3;               // 0..63
  const int gch = (tid & 7) ^ (srow & 7);  // inverse of read swizzle
  const bf16* wsrc = Wf + (long)(n0 + srow) * K_DIM + gch * 8;
  auto stageB = [&](int tt, int h) {
    bf16* dst = smem + (tt & 1) * 32768 + 16384 + h * 8192 + tid * 8;
    const bf16* s = wsrc + (long)h * 128 * K_DIM + tt * 64;
    async16(s, dst);
    async16(s + 64 * K_DIM, dst + 4096);
  };

  // ---- A staging (reg-staged fp32 -> bf16, swizzled ds_write) ----
  const int arow = tid >> 2;  // 0..127
  const int acp = tid & 3;    // chunk pair: global chunks 2acp, 2acp+1
  const int ar7 = arow & 7;
  const int aslot0 = (2 * acp) ^ ar7;
  const int aslot1 = (2 * acp + 1) ^ ar7;
  const float* asrc = Xf + (m0 + arow) * K_DIM + acp * 16;

  f32x4 rA0[4], rA1[4];  // single in-flight A set (halves 0/1)
  auto loadA0 = [&](int tt) {
    const float* s = asrc + tt * 64;
#pragma unroll
    for (int i = 0; i < 4; ++i) rA0[i] = *(const f32x4*)(s + i * 4);
  };
  auto loadA1 = [&](int tt) {
    const float* s = asrc + (long)128 * K_DIM + tt * 64;
#pragma unroll
    for (int i = 0; i < 4; ++i) rA1[i] = *(const f32x4*)(s + i * 4);
  };
  auto writeA0 = [&](int tt) {  // cvt+write from rA0
    bf16* dst = smem + (tt & 1) * 32768 + arow * 64;
    bf16x8 c0, c1;
#pragma unroll
    for (int j = 0; j < 4; ++j) {
      c0[j] = (bf16)rA0[0][j];
      c0[4 + j] = (bf16)rA0[1][j];
      c1[j] = (bf16)rA0[2][j];
      c1[4 + j] = (bf16)rA0[3][j];
    }
    *(bf16x8*)(dst + aslot0 * 8) = c0;
    *(bf16x8*)(dst + aslot1 * 8) = c1;
  };
  auto writeA1 = [&](int tt) {  // cvt+write from rA1
    bf16* dst = smem + (tt & 1) * 32768 + 8192 + arow * 64;
    bf16x8 c0, c1;
#pragma unroll
    for (int j = 0; j < 4; ++j) {
      c0[j] = (bf16)rA1[0][j];
      c0[4 + j] = (bf16)rA1[1][j];
      c1[j] = (bf16)rA1[2][j];
      c1[4 + j] = (bf16)rA1[3][j];
    }
    *(bf16x8*)(dst + aslot0 * 8) = c0;
    *(bf16x8*)(dst + aslot1 * 8) = c1;
  };

  // fragment read offsets (XOR bank swizzle); kk=1 -> elem offset ^32
  const int key = l15 & 7;
  const int ck0 = lq ^ key;
  const int eA = (wm * 128 + l15) * 64 + ck0 * 8;
  const int eB = (wn * 64 + l15) * 64 + ck0 * 8;

  f32x4 acc[8][4] = {};

  // ---- prologue ----
  loadA0(0); loadA1(0);
  stageB(0, 0); stageB(0, 1); stageB(1, 0); stageB(1, 1);
  writeA0(0); writeA1(0);        // cvt waits on loadA(0) only (oldest)
  loadA0(1); loadA1(1);          // rA now holds A(1)
  VMW(12);                       // retire B(0); keep B(1)+loadA(1) in flight
  asm volatile("s_waitcnt lgkmcnt(0)" ::: "memory");
  BAR();

  for (int t = 0; t < NT; ++t) {
    const bf16* Ab = smem + (t & 1) * 32768;
    const bf16* Bb = Ab + 16384;
    bf16x8 B0[4], B1[4];
    {  // p1: (m0-3, kk0)
      bf16x8 A[4];
#pragma unroll
      for (int i = 0; i < 4; ++i) A[i] = *(const bf16x8*)(Ab + eA + i * 1024);
#pragma unroll
      for (int i = 0; i < 4; ++i) B0[i] = *(const bf16x8*)(Bb + eB + i * 1024);
      BAR();
      LGKM(0);
      __builtin_amdgcn_s_setprio(1);
#pragma unroll
      for (int m = 0; m < 4; ++m)
#pragma unroll
        for (int n = 0; n < 4; ++n) MFMA(acc[m][n], A[m], B0[n]);
      __builtin_amdgcn_s_setprio(0);
      BAR();
    }
    {  // p2: (m0-3, kk1)
      bf16x8 A[4];
#pragma unroll
      for (int i = 0; i < 4; ++i)
        A[i] = *(const bf16x8*)(Ab + (eA ^ 32) + i * 1024);
#pragma unroll
      for (int i = 0; i < 4; ++i)
        B1[i] = *(const bf16x8*)(Bb + (eB ^ 32) + i * 1024);
      BAR();
      LGKM(0);
      __builtin_amdgcn_s_setprio(1);
#pragma unroll
      for (int m = 0; m < 4; ++m)
#pragma unroll
        for (int n = 0; n < 4; ++n) MFMA(acc[m][n], A[m], B1[n]);
      __builtin_amdgcn_s_setprio(0);
      BAR();
    }
    {  // p3: (m4-7, kk0); stage B(t+2) lo; write A(t+1) h0; reload rA0
      bf16x8 A[4];
#pragma unroll
      for (int i = 0; i < 4; ++i)
        A[i] = *(const bf16x8*)(Ab + eA + 4096 + i * 1024);
      __builtin_amdgcn_sched_barrier(0);  // pin: frag reads precede ds_writes
      if (t < NT - 2) stageB(t + 2, 0);
      if (t < NT - 1) writeA0(t + 1);
      if (t < NT - 2) loadA0(t + 2);  // WAR-safe: after cvt reads
      BAR();
      if (t < NT - 1) {
        LGKM(2);  // 4 reads done; 2 A-writes retire under MFMA
      } else {
        LGKM(0);  // no writes issued this phase
      }
      __builtin_amdgcn_s_setprio(1);
#pragma unroll
      for (int m = 0; m < 4; ++m)
#pragma unroll
        for (int n = 0; n < 4; ++n) MFMA(acc[4 + m][n], A[m], B0[n]);
      __builtin_amdgcn_s_setprio(0);
      BAR();
    }
    {  // p4: (m4-7, kk1); stage B(t+2) hi; write A(t+1) h1; reload rA1
      bf16x8 A[4];
#pragma unroll
      for (int i = 0; i < 4; ++i)
        A[i] = *(const bf16x8*)(Ab + (eA ^ 32) + 4096 + i * 1024);
      __builtin_amdgcn_sched_barrier(0);  // pin: frag reads precede ds_writes
      if (t < NT - 2) stageB(t + 2, 1);
      if (t < NT - 1) writeA1(t + 1);
      if (t < NT - 2) loadA1(t + 2);
      BAR();
      if (t < NT - 1) {
        LGKM(2);  // p3 writes + p4 reads done; p4's 2 writes outstanding
      } else {
        LGKM(0);
      }
      __builtin_amdgcn_s_setprio(1);
#pragma unroll
      for (int m = 0; m < 4; ++m)
#pragma unroll
        for (int n = 0; n < 4; ++n) MFMA(acc[4 + m][n], A[m], B1[n]);
      __builtin_amdgcn_s_setprio(0);
      // drain this tile's A-writes before the boundary barrier so next
      // tile's cross-wave p1 reads see them (writes retired under MFMA).
      if (t < NT - 1) LGKM(0);
      // boundary: B(t+1) already retired by writeA's cvt-dependency waits;
      // 12 newest (stageB(t+2) 4 + loadA(t+2) 8) stay in flight.
      if (t < NT - 2) {
        VMW(12);
      } else if (t == NT - 2) {
        VMW(0);
      }
      BAR();
    }
  }

  // epilogue: C/D layout col = lane&15, row = lq*4 + reg
  const long crow0 = m0 + wm * 128 + lq * 4;
  const int ccol0 = n0 + wn * 64 + l15;
  float bn4[4];
#pragma unroll
  for (int n = 0; n < 4; ++n) bn4[n] = bias[ccol0 + n * 16];
#pragma unroll
  for (int m = 0; m < 8; ++m)
#pragma unroll
    for (int n = 0; n < 4; ++n) {
      const int col = ccol0 + n * 16;
#pragma unroll
      for (int i = 0; i < 4; ++i)
        Y[(crow0 + m * 16 + i) * N_DIM + col] = acc[m][n][i] + bn4[n];
    }
}

extern "C" void kernel_launch(void* const* d_in, const int* in_sizes, int n_in,
                              void* d_out, int out_size, void* d_ws, size_t ws_size,
                              hipStream_t stream) {
  const float* x = (const float*)d_in[0];
  const float* W = (const float*)d_in[1];
  const float* b = (const float*)d_in[2];
  const float* lA = (const float*)d_in[3];
  const float* lB = (const float*)d_in[4];
  float* y = (float*)d_out;

  bf16* weff = (bf16*)d_ws;  // 2 MB

  weff_kernel<<<dim3(1024), dim3(256), 0, stream>>>(W, lA, lB, weff);

  const int grid = (M_DIM / 256) * (N_DIM / 256);  // 512
  gemm8f<<<dim3(grid), dim3(512), 0, stream>>>(x, weff, b, y);
}